// Round 13
// baseline (150.694 us; speedup 1.0000x reference)
//
#include <hip/hip_runtime.h>
#include <hip/hip_bf16.h>
#include <math.h>

typedef __bf16 bf16x8 __attribute__((ext_vector_type(8)));
typedef float f32x4 __attribute__((ext_vector_type(4)));

__device__ __forceinline__ unsigned short f2bf(float x) {
    union { float f; unsigned int u; } v; v.f = x;
    unsigned int r = v.u + 0x7fffu + ((v.u >> 16) & 1u);  // round-to-nearest-even
    return (unsigned short)(r >> 16);
}
__device__ __forceinline__ float gelu_exact(float v) {
    return 0.5f * v * (1.0f + erff(v * 0.70710678118654752f));
}

// ---------------------------------------------------------------------------
// prep: blocks [0,4096)    -> span pooling into hp (4096 x 3072 bf16)
//       blocks [4096,4864) -> W1 fp32 -> bf16 (256x3072)
//       blocks [4864,4896) -> W2 fp32 -> bf16 (128x256)
// ---------------------------------------------------------------------------
__global__ __launch_bounds__(256) void prep_kernel(const float* __restrict__ hs,
                                                   const int* __restrict__ spans,
                                                   const float* __restrict__ W1,
                                                   const float* __restrict__ W2,
                                                   unsigned short* __restrict__ hp,
                                                   unsigned short* __restrict__ w1b,
                                                   unsigned short* __restrict__ w2b) {
    const int blk = blockIdx.x;
    const int tid = threadIdx.x;

    if (blk >= 4096) {
        if (blk < 4864) {                     // W1 convert: 196608 float4s
            const int i = (blk - 4096) * 256 + tid;
            float4 f = ((const float4*)W1)[i];
            ushort4 u;
            u.x = f2bf(f.x); u.y = f2bf(f.y); u.z = f2bf(f.z); u.w = f2bf(f.w);
            ((ushort4*)w1b)[i] = u;
        } else {                              // W2 convert: 8192 float4s
            const int i = (blk - 4864) * 256 + tid;
            float4 f = ((const float4*)W2)[i];
            ushort4 u;
            u.x = f2bf(f.x); u.y = f2bf(f.y); u.z = f2bf(f.z); u.w = f2bf(f.w);
            ((ushort4*)w2b)[i] = u;
        }
        return;
    }

    const int pair = blk;                     // b*Q + q, Q=128
    const int b = pair >> 7;

    // dtype probe: int64 spans -> word 1 is high half of asp_s[0] (== 0);
    // int32 spans -> it's asp_e[0] which is always >= 2.
    const bool is64 = (spans[1] == 0);
    int s_a, e_a, s_o, e_o;
    if (is64) {
        s_a = spans[(pair * 4 + 0) * 2]; e_a = spans[(pair * 4 + 1) * 2];
        s_o = spans[(pair * 4 + 2) * 2]; e_o = spans[(pair * 4 + 3) * 2];
    } else {
        s_a = spans[pair * 4 + 0]; e_a = spans[pair * 4 + 1];
        s_o = spans[pair * 4 + 2]; e_o = spans[pair * 4 + 3];
    }

    const float4* base = (const float4*)hs + (size_t)b * 512 * 256;  // L=512, H/4=256

    float4 A, O;
    if (s_a >= 2 && e_a >= s_a) {
        float sx = 0.f, sy = 0.f, sz = 0.f, sw = 0.f;
        for (int t = s_a; t <= e_a; ++t) {
            float4 v = base[t * 256 + tid];
            sx += v.x; sy += v.y; sz += v.z; sw += v.w;
        }
        float inv = 1.0f / (float)(e_a - s_a + 1);
        A.x = sx * inv; A.y = sy * inv; A.z = sz * inv; A.w = sw * inv;
    } else {
        A = base[256 + tid];                  // sep token, row 1
    }
    if (s_o >= 2 && e_o >= s_o) {
        float sx = 0.f, sy = 0.f, sz = 0.f, sw = 0.f;
        for (int t = s_o; t <= e_o; ++t) {
            float4 v = base[t * 256 + tid];
            sx += v.x; sy += v.y; sz += v.z; sw += v.w;
        }
        float inv = 1.0f / (float)(e_o - s_o + 1);
        O.x = sx * inv; O.y = sy * inv; O.z = sz * inv; O.w = sw * inv;
    } else {
        O = base[256 + tid];
    }

    unsigned short* row = hp + (size_t)pair * 3072;
    const int d = tid * 4;
    ushort4 pa, po, pp;
    pa.x = f2bf(A.x); pa.y = f2bf(A.y); pa.z = f2bf(A.z); pa.w = f2bf(A.w);
    po.x = f2bf(O.x); po.y = f2bf(O.y); po.z = f2bf(O.z); po.w = f2bf(O.w);
    pp.x = f2bf(A.x * O.x); pp.y = f2bf(A.y * O.y);
    pp.z = f2bf(A.z * O.z); pp.w = f2bf(A.w * O.w);
    *(ushort4*)(row + d) = pa;
    *(ushort4*)(row + 1024 + d) = po;
    *(ushort4*)(row + 2048 + d) = pp;
}

// ---------------------------------------------------------------------------
// gemm1_gelu v4: x1 = gelu(hp @ w1b^T + b1) -> bf16. No split-K, no atomics.
// BM=64, BN=64, BK=128, K=3072 (24 iters). grid (64, 4) = 256 blocks (1/CU).
// L2 read traffic: A 4x24=96MB + B 64x1.5=96MB = 196MB (~5.6us at L2 BW) vs
// 292MB for the BM=32 shape. LDS 64 KB double-buffered; waves 2x2, wave tile
// 32x32 = 16 MFMA/iter. Staging 32KB/iter (8 global_load_lds per thread) is
// throughput-regime; dbuf issues next tile right after the barrier.
// XOR chunk swizzle (16 chunks/row, pc = ((c&7)^(row&7)) | (c&8)).
// ---------------------------------------------------------------------------
__global__ __launch_bounds__(256, 2) void gemm1_gelu(const unsigned short* __restrict__ A,
                                                     const unsigned short* __restrict__ Bw,
                                                     const float* __restrict__ b1,
                                                     unsigned short* __restrict__ x1) {
    __shared__ __align__(16) unsigned short As[2 * 64 * 128];   // 32 KB
    __shared__ __align__(16) unsigned short Bs[2 * 64 * 128];   // 32 KB

    const int tid = threadIdx.x;
    const int lane = tid & 63;
    const int wid = tid >> 6;
    const int quad = lane >> 4;
    const int l16 = lane & 15;
    const int wM = (wid >> 1) * 32;
    const int wN = (wid & 1) * 32;
    const int m0 = blockIdx.x * 64;
    const int n0 = blockIdx.y * 64;

    // staging: slot s -> row = s>>4, chunk c = s&15; source chunk XOR-swizzled
    const int srow = tid >> 4;                // 0..15 (+p*16)
    const int ac = tid & 15;
    const unsigned short* Aptr[4];
    const unsigned short* Bptr[4];
#pragma unroll
    for (int p = 0; p < 4; ++p) {
        const int row = srow + p * 16;        // 0..63
        const int lch = ((ac & 7) ^ (row & 7)) | (ac & 8);
        Aptr[p] = A + (size_t)(m0 + row) * 3072 + lch * 8;
        Bptr[p] = Bw + (size_t)(n0 + row) * 3072 + lch * 8;
    }

    // fragment LDS offsets (halfwords): K-frag h (4 per iter), chunk c = h*4+quad
    int aoff[2][4], boff[2][4];
#pragma unroll
    for (int h = 0; h < 4; ++h) {
        const int c = h * 4 + quad;
#pragma unroll
        for (int i = 0; i < 2; ++i) {
            const int rowa = wM + i * 16 + l16;
            const int pca = ((c & 7) ^ (rowa & 7)) | (c & 8);
            aoff[i][h] = rowa * 128 + pca * 8;
            const int rowb = wN + i * 16 + l16;
            const int pcb = ((c & 7) ^ (rowb & 7)) | (c & 8);
            boff[i][h] = rowb * 128 + pcb * 8;
        }
    }

    f32x4 acc[2][2] = {};

    // prologue: tile 0 -> buffer 0
#pragma unroll
    for (int p = 0; p < 4; ++p) {
        __builtin_amdgcn_global_load_lds(
            (const __attribute__((address_space(1))) void*)Aptr[p],
            (__attribute__((address_space(3))) void*)(&As[(p * 256 + tid) * 8]), 16, 0, 0);
        __builtin_amdgcn_global_load_lds(
            (const __attribute__((address_space(1))) void*)Bptr[p],
            (__attribute__((address_space(3))) void*)(&Bs[(p * 256 + tid) * 8]), 16, 0, 0);
    }

    for (int it = 0; it < 24; ++it) {
        const int cur = it & 1;
        __syncthreads();                      // drains pending stage (vmcnt 0)
        if (it + 1 < 24) {
            const int nxt = cur ^ 1;
            const int kadv = (it + 1) * 128;  // halfwords along K
#pragma unroll
            for (int p = 0; p < 4; ++p) {
                __builtin_amdgcn_global_load_lds(
                    (const __attribute__((address_space(1))) void*)(Aptr[p] + kadv),
                    (__attribute__((address_space(3))) void*)(&As[nxt * 8192 + (p * 256 + tid) * 8]), 16, 0, 0);
                __builtin_amdgcn_global_load_lds(
                    (const __attribute__((address_space(1))) void*)(Bptr[p] + kadv),
                    (__attribute__((address_space(3))) void*)(&Bs[nxt * 8192 + (p * 256 + tid) * 8]), 16, 0, 0);
            }
        }
#pragma unroll
        for (int h = 0; h < 4; ++h) {
            bf16x8 a0 = *(const bf16x8*)&As[cur * 8192 + aoff[0][h]];
            bf16x8 a1 = *(const bf16x8*)&As[cur * 8192 + aoff[1][h]];
            bf16x8 b0 = *(const bf16x8*)&Bs[cur * 8192 + boff[0][h]];
            bf16x8 b1 = *(const bf16x8*)&Bs[cur * 8192 + boff[1][h]];
            acc[0][0] = __builtin_amdgcn_mfma_f32_16x16x32_bf16(a0, b0, acc[0][0], 0, 0, 0);
            acc[0][1] = __builtin_amdgcn_mfma_f32_16x16x32_bf16(a0, b1, acc[0][1], 0, 0, 0);
            acc[1][0] = __builtin_amdgcn_mfma_f32_16x16x32_bf16(a1, b0, acc[1][0], 0, 0, 0);
            acc[1][1] = __builtin_amdgcn_mfma_f32_16x16x32_bf16(a1, b1, acc[1][1], 0, 0, 0);
        }
    }

    // epilogue: bias + gelu -> bf16; C/D map: col=l16, row=quad*4+reg
#pragma unroll
    for (int ni = 0; ni < 2; ++ni) {
        const int n = n0 + wN + ni * 16 + l16;
        const float bn = b1[n];
#pragma unroll
        for (int mh = 0; mh < 2; ++mh) {
#pragma unroll
            for (int rr = 0; rr < 4; ++rr) {
                const int m = m0 + wM + mh * 16 + quad * 4 + rr;
                x1[(size_t)m * 256 + n] = f2bf(gelu_exact(acc[mh][ni][rr] + bn));
            }
        }
    }
}

// ---------------------------------------------------------------------------
// mlp2_head v2 (single-stage): 32 pairs/block, grid 128.
// Stage whole x1 tile (16 KB) + whole w2b (64 KB) via global_load_lds with
// XOR chunk swizzle, ONE barrier, then 32 MFMA/wave with no further barriers.
// ---------------------------------------------------------------------------
__global__ __launch_bounds__(256) void mlp2_head(const unsigned short* __restrict__ x1,
                                                 const unsigned short* __restrict__ w2b,
                                                 const float* __restrict__ b2,
                                                 const float* __restrict__ W3,
                                                 const float* __restrict__ b3,
                                                 const float* __restrict__ mask,
                                                 float* __restrict__ out) {
    __shared__ __align__(16) unsigned char smem[98304];
    unsigned short* Xs = (unsigned short*)smem;            // 32 x 256 hw (swizzled)
    unsigned short* Ws = (unsigned short*)(smem + 16384);  // 128 x 256 hw (swizzled)
    float*          X2 = (float*)(smem + 81920);           // 32 x 128 fp32

    const int tid = threadIdx.x;
    const int lane = tid & 63;
    const int wid = tid >> 6;
    const int quad = lane >> 4;
    const int l16 = lane & 15;
    const int wM = (wid >> 1) * 16;   // waves 2x2: wave tile 16 pairs x 64 cols
    const int wN = (wid & 1) * 64;
    const int m0 = blockIdx.x * 32;

    // stage Xs: 1024 slots; slot s -> row=s>>5, c=s&31, swizzled source chunk
#pragma unroll
    for (int p = 0; p < 4; ++p) {
        const int s = p * 256 + tid;
        const int row = s >> 5;
        const int c = s & 31;
        const int lch = (c & 24) | ((c & 7) ^ (row & 7));
        __builtin_amdgcn_global_load_lds(
            (const __attribute__((address_space(1))) void*)(x1 + (size_t)(m0 + row) * 256 + lch * 8),
            (__attribute__((address_space(3))) void*)(&Xs[s * 8]), 16, 0, 0);
    }
    // stage Ws: 4096 slots
#pragma unroll
    for (int p = 0; p < 16; ++p) {
        const int s = p * 256 + tid;
        const int row = s >> 5;
        const int c = s & 31;
        const int lch = (c & 24) | ((c & 7) ^ (row & 7));
        __builtin_amdgcn_global_load_lds(
            (const __attribute__((address_space(1))) void*)(w2b + (size_t)row * 256 + lch * 8),
            (__attribute__((address_space(3))) void*)(&Ws[s * 8]), 16, 0, 0);
    }
    __syncthreads();

    // GEMM2: 8 K-frags, 4 MFMA each per wave
    f32x4 acc[4] = {};
#pragma unroll
    for (int h = 0; h < 8; ++h) {
        const int c = h * 4 + quad;
        const int rowa = wM + l16;
        const int pca = (c & 24) | ((c & 7) ^ (rowa & 7));
        bf16x8 a = *(const bf16x8*)&Xs[rowa * 256 + pca * 8];
#pragma unroll
        for (int ni = 0; ni < 4; ++ni) {
            const int rowb = wN + ni * 16 + l16;
            const int pcb = (c & 24) | ((c & 7) ^ (rowb & 7));
            bf16x8 b = *(const bf16x8*)&Ws[rowb * 256 + pcb * 8];
            acc[ni] = __builtin_amdgcn_mfma_f32_16x16x32_bf16(a, b, acc[ni], 0, 0, 0);
        }
    }

    // x2 = gelu(acc + b2) -> X2 (fp32 LDS)
#pragma unroll
    for (int ni = 0; ni < 4; ++ni) {
        const int n = wN + ni * 16 + l16;
        const float bn = b2[n];
#pragma unroll
        for (int rr = 0; rr < 4; ++rr) {
            const int m = wM + quad * 4 + rr;
            X2[m * 128 + n] = gelu_exact(acc[ni][rr] + bn);
        }
    }
    __syncthreads();

    // head: 8 threads per pair, 16 cols each
    const int p = tid >> 3;           // pair-in-block 0..31
    const int cc = (tid & 7) * 16;
    float a0 = 0.f, a1 = 0.f;
#pragma unroll
    for (int j = 0; j < 16; ++j) {
        const float xv = X2[p * 128 + cc + j];
        a0 += xv * W3[cc + j];
        a1 += xv * W3[128 + cc + j];
    }
    a0 += __shfl_xor(a0, 1); a0 += __shfl_xor(a0, 2); a0 += __shfl_xor(a0, 4);
    a1 += __shfl_xor(a1, 1); a1 += __shfl_xor(a1, 2); a1 += __shfl_xor(a1, 4);
    if ((tid & 7) == 0) {
        const int pair = m0 + p;
        const float mk = (mask[pair] >= 0.5f) ? 1.0f : 0.0f;
        out[pair * 2 + 0] = ((1.0f / (1.0f + expf(-(a0 + b3[0])))) * 8.0f + 1.0f) * mk;
        out[pair * 2 + 1] = ((1.0f / (1.0f + expf(-(a1 + b3[1])))) * 8.0f + 1.0f) * mk;
    }
}

// ---------------------------------------------------------------------------
extern "C" void kernel_launch(void* const* d_in, const int* in_sizes, int n_in,
                              void* d_out, int out_size, void* d_ws, size_t ws_size,
                              hipStream_t stream) {
    const float* hs   = (const float*)d_in[0];
    const int*   spans= (const int*)d_in[1];
    const float* mask = (const float*)d_in[2];
    const float* W1   = (const float*)d_in[3];
    const float* b1   = (const float*)d_in[4];
    const float* W2   = (const float*)d_in[5];
    const float* b2   = (const float*)d_in[6];
    const float* W3   = (const float*)d_in[7];
    const float* b3   = (const float*)d_in[8];
    float* out = (float*)d_out;

    // ws: hp bf16 4096x3072 [0, 25165824); w1b bf16 256x3072 [25165824, +1.5MB);
    // x1 bf16 4096x256 [26738688, +2MB); w2b bf16 128x256 [28835840, +64KB).
    unsigned short* hp  = (unsigned short*)d_ws;
    unsigned short* w1b = (unsigned short*)((char*)d_ws + 25165824);
    unsigned short* x1  = (unsigned short*)((char*)d_ws + 26738688);
    unsigned short* w2b = (unsigned short*)((char*)d_ws + 28835840);

    prep_kernel<<<dim3(4896), dim3(256), 0, stream>>>(hs, spans, W1, W2, hp, w1b, w2b);
    gemm1_gelu<<<dim3(64, 4), dim3(256), 0, stream>>>(hp, w1b, b1, x1);
    mlp2_head<<<dim3(128), dim3(256), 0, stream>>>(x1, w2b, b2, W3, b3, mask, out);
}

// Round 14
// 145.952 us; speedup vs baseline: 1.0325x; 1.0325x over previous
//
#include <hip/hip_runtime.h>
#include <hip/hip_bf16.h>
#include <math.h>

typedef __bf16 bf16x8 __attribute__((ext_vector_type(8)));
typedef float f32x4 __attribute__((ext_vector_type(4)));

__device__ __forceinline__ unsigned short f2bf(float x) {
    union { float f; unsigned int u; } v; v.f = x;
    unsigned int r = v.u + 0x7fffu + ((v.u >> 16) & 1u);  // round-to-nearest-even
    return (unsigned short)(r >> 16);
}
__device__ __forceinline__ float gelu_exact(float v) {
    return 0.5f * v * (1.0f + erff(v * 0.70710678118654752f));
}

// ---------------------------------------------------------------------------
// prep: blocks [0,4096)    -> span pooling into hp (4096 x 3072 bf16)
//       blocks [4096,4864) -> W1 fp32 -> bf16 (256x3072)
//       blocks [4864,4896) -> W2 fp32 -> bf16 (128x256)
// ---------------------------------------------------------------------------
__global__ __launch_bounds__(256) void prep_kernel(const float* __restrict__ hs,
                                                   const int* __restrict__ spans,
                                                   const float* __restrict__ W1,
                                                   const float* __restrict__ W2,
                                                   unsigned short* __restrict__ hp,
                                                   unsigned short* __restrict__ w1b,
                                                   unsigned short* __restrict__ w2b) {
    const int blk = blockIdx.x;
    const int tid = threadIdx.x;

    if (blk >= 4096) {
        if (blk < 4864) {                     // W1 convert: 196608 float4s
            const int i = (blk - 4096) * 256 + tid;
            float4 f = ((const float4*)W1)[i];
            ushort4 u;
            u.x = f2bf(f.x); u.y = f2bf(f.y); u.z = f2bf(f.z); u.w = f2bf(f.w);
            ((ushort4*)w1b)[i] = u;
        } else {                              // W2 convert: 8192 float4s
            const int i = (blk - 4864) * 256 + tid;
            float4 f = ((const float4*)W2)[i];
            ushort4 u;
            u.x = f2bf(f.x); u.y = f2bf(f.y); u.z = f2bf(f.z); u.w = f2bf(f.w);
            ((ushort4*)w2b)[i] = u;
        }
        return;
    }

    const int pair = blk;                     // b*Q + q, Q=128
    const int b = pair >> 7;

    // dtype probe: int64 spans -> word 1 is high half of asp_s[0] (== 0);
    // int32 spans -> it's asp_e[0] which is always >= 2.
    const bool is64 = (spans[1] == 0);
    int s_a, e_a, s_o, e_o;
    if (is64) {
        s_a = spans[(pair * 4 + 0) * 2]; e_a = spans[(pair * 4 + 1) * 2];
        s_o = spans[(pair * 4 + 2) * 2]; e_o = spans[(pair * 4 + 3) * 2];
    } else {
        s_a = spans[pair * 4 + 0]; e_a = spans[pair * 4 + 1];
        s_o = spans[pair * 4 + 2]; e_o = spans[pair * 4 + 3];
    }

    const float4* base = (const float4*)hs + (size_t)b * 512 * 256;  // L=512, H/4=256

    float4 A, O;
    if (s_a >= 2 && e_a >= s_a) {
        float sx = 0.f, sy = 0.f, sz = 0.f, sw = 0.f;
        for (int t = s_a; t <= e_a; ++t) {
            float4 v = base[t * 256 + tid];
            sx += v.x; sy += v.y; sz += v.z; sw += v.w;
        }
        float inv = 1.0f / (float)(e_a - s_a + 1);
        A.x = sx * inv; A.y = sy * inv; A.z = sz * inv; A.w = sw * inv;
    } else {
        A = base[256 + tid];                  // sep token, row 1
    }
    if (s_o >= 2 && e_o >= s_o) {
        float sx = 0.f, sy = 0.f, sz = 0.f, sw = 0.f;
        for (int t = s_o; t <= e_o; ++t) {
            float4 v = base[t * 256 + tid];
            sx += v.x; sy += v.y; sz += v.z; sw += v.w;
        }
        float inv = 1.0f / (float)(e_o - s_o + 1);
        O.x = sx * inv; O.y = sy * inv; O.z = sz * inv; O.w = sw * inv;
    } else {
        O = base[256 + tid];
    }

    unsigned short* row = hp + (size_t)pair * 3072;
    const int d = tid * 4;
    ushort4 pa, po, pp;
    pa.x = f2bf(A.x); pa.y = f2bf(A.y); pa.z = f2bf(A.z); pa.w = f2bf(A.w);
    po.x = f2bf(O.x); po.y = f2bf(O.y); po.z = f2bf(O.z); po.w = f2bf(O.w);
    pp.x = f2bf(A.x * O.x); pp.y = f2bf(A.y * O.y);
    pp.z = f2bf(A.z * O.z); pp.w = f2bf(A.w * O.w);
    *(ushort4*)(row + d) = pa;
    *(ushort4*)(row + 1024 + d) = po;
    *(ushort4*)(row + 2048 + d) = pp;
}

// ---------------------------------------------------------------------------
// gemm1_gelu v3 (measured optimum): x1 = gelu(hp @ w1b^T + b1) -> bf16.
// BM=32, BN=64, BK=192, K=3072 (16 iters). grid (128, 4) = 512 blocks (2/CU).
// 2 blocks/CU is REQUIRED: one block's barrier drain co-schedules with the
// other's compute (1 blk/CU variants measured slower: R8 42us, R13 +4us).
// LDS 72 KB double-buffered; 4 waves, wave owns 16 N-cols x 32 M-rows:
// 12 MFMA/iter. global_load_lds w16, XOR chunk swizzle (24 chunks/row,
// pc = (c&24)|((c&7)^(row&7))); read side agrees -> 2-way banks (free).
// ---------------------------------------------------------------------------
__global__ __launch_bounds__(256, 2) void gemm1_gelu(const unsigned short* __restrict__ A,
                                                     const unsigned short* __restrict__ Bw,
                                                     const float* __restrict__ b1,
                                                     unsigned short* __restrict__ x1) {
    __shared__ __align__(16) unsigned short As[2 * 32 * 192];   // 24 KB
    __shared__ __align__(16) unsigned short Bs[2 * 64 * 192];   // 48 KB

    const int tid = threadIdx.x;
    const int lane = tid & 63;
    const int wid = tid >> 6;
    const int quad = lane >> 4;
    const int l16 = lane & 15;
    const int m0 = blockIdx.x * 32;
    const int n0 = blockIdx.y * 64;

    // staging sources: slot s (16B) -> row = s/24, chunk c = s%24, XOR-swizzled
    const unsigned short* Aptr[3];
#pragma unroll
    for (int p = 0; p < 3; ++p) {
        const int s = p * 256 + tid;          // 0..767
        const int row = s / 24;
        const int c = s - row * 24;
        const int lch = (c & 24) | ((c & 7) ^ (row & 7));
        Aptr[p] = A + (size_t)(m0 + row) * 3072 + lch * 8;
    }
    const unsigned short* Bptr[6];
#pragma unroll
    for (int p = 0; p < 6; ++p) {
        const int s = p * 256 + tid;          // 0..1535
        const int row = s / 24;
        const int c = s - row * 24;
        const int lch = (c & 24) | ((c & 7) ^ (row & 7));
        Bptr[p] = Bw + (size_t)(n0 + row) * 3072 + lch * 8;
    }

    // fragment LDS offsets (halfwords): K-frag h (6 per iter), chunk c = h*4+quad
    int aoff[2][6], boff[6];
#pragma unroll
    for (int h = 0; h < 6; ++h) {
        const int c = h * 4 + quad;
#pragma unroll
        for (int mh = 0; mh < 2; ++mh) {
            const int row = mh * 16 + l16;
            const int pc = (c & 24) | ((c & 7) ^ (row & 7));
            aoff[mh][h] = row * 192 + pc * 8;
        }
        const int brow = wid * 16 + l16;
        const int pcb = (c & 24) | ((c & 7) ^ (brow & 7));
        boff[h] = brow * 192 + pcb * 8;
    }

    f32x4 acc[2] = {};

    // prologue: tile 0 -> buffer 0
#pragma unroll
    for (int p = 0; p < 3; ++p)
        __builtin_amdgcn_global_load_lds(
            (const __attribute__((address_space(1))) void*)Aptr[p],
            (__attribute__((address_space(3))) void*)(&As[(p * 256 + tid) * 8]), 16, 0, 0);
#pragma unroll
    for (int p = 0; p < 6; ++p)
        __builtin_amdgcn_global_load_lds(
            (const __attribute__((address_space(1))) void*)Bptr[p],
            (__attribute__((address_space(3))) void*)(&Bs[(p * 256 + tid) * 8]), 16, 0, 0);

    for (int it = 0; it < 16; ++it) {
        const int cur = it & 1;
        __syncthreads();                      // drains pending stage (vmcnt 0)
        if (it + 1 < 16) {
            const int nxt = cur ^ 1;
            const int kadv = (it + 1) * 192;  // halfwords along K
#pragma unroll
            for (int p = 0; p < 3; ++p)
                __builtin_amdgcn_global_load_lds(
                    (const __attribute__((address_space(1))) void*)(Aptr[p] + kadv),
                    (__attribute__((address_space(3))) void*)(&As[nxt * 6144 + (p * 256 + tid) * 8]), 16, 0, 0);
#pragma unroll
            for (int p = 0; p < 6; ++p)
                __builtin_amdgcn_global_load_lds(
                    (const __attribute__((address_space(1))) void*)(Bptr[p] + kadv),
                    (__attribute__((address_space(3))) void*)(&Bs[nxt * 12288 + (p * 256 + tid) * 8]), 16, 0, 0);
        }
#pragma unroll
        for (int h = 0; h < 6; ++h) {
            bf16x8 b = *(const bf16x8*)&Bs[cur * 12288 + boff[h]];
#pragma unroll
            for (int mh = 0; mh < 2; ++mh) {
                bf16x8 a = *(const bf16x8*)&As[cur * 6144 + aoff[mh][h]];
                acc[mh] = __builtin_amdgcn_mfma_f32_16x16x32_bf16(a, b, acc[mh], 0, 0, 0);
            }
        }
    }

    // epilogue: bias + gelu -> bf16; C/D map: col=l16, row=quad*4+reg
    const int n = n0 + wid * 16 + l16;
    const float bn = b1[n];
#pragma unroll
    for (int mh = 0; mh < 2; ++mh) {
#pragma unroll
        for (int rr = 0; rr < 4; ++rr) {
            const int m = m0 + mh * 16 + quad * 4 + rr;
            x1[(size_t)m * 256 + n] = f2bf(gelu_exact(acc[mh][rr] + bn));
        }
    }
}

// ---------------------------------------------------------------------------
// mlp2_head v2 (single-stage): 32 pairs/block, grid 128.
// Stage whole x1 tile (16 KB) + whole w2b (64 KB) via global_load_lds with
// XOR chunk swizzle, ONE barrier, then 32 MFMA/wave with no further barriers.
// ---------------------------------------------------------------------------
__global__ __launch_bounds__(256) void mlp2_head(const unsigned short* __restrict__ x1,
                                                 const unsigned short* __restrict__ w2b,
                                                 const float* __restrict__ b2,
                                                 const float* __restrict__ W3,
                                                 const float* __restrict__ b3,
                                                 const float* __restrict__ mask,
                                                 float* __restrict__ out) {
    __shared__ __align__(16) unsigned char smem[98304];
    unsigned short* Xs = (unsigned short*)smem;            // 32 x 256 hw (swizzled)
    unsigned short* Ws = (unsigned short*)(smem + 16384);  // 128 x 256 hw (swizzled)
    float*          X2 = (float*)(smem + 81920);           // 32 x 128 fp32

    const int tid = threadIdx.x;
    const int lane = tid & 63;
    const int wid = tid >> 6;
    const int quad = lane >> 4;
    const int l16 = lane & 15;
    const int wM = (wid >> 1) * 16;   // waves 2x2: wave tile 16 pairs x 64 cols
    const int wN = (wid & 1) * 64;
    const int m0 = blockIdx.x * 32;

    // stage Xs: 1024 slots; slot s -> row=s>>5, c=s&31, swizzled source chunk
#pragma unroll
    for (int p = 0; p < 4; ++p) {
        const int s = p * 256 + tid;
        const int row = s >> 5;
        const int c = s & 31;
        const int lch = (c & 24) | ((c & 7) ^ (row & 7));
        __builtin_amdgcn_global_load_lds(
            (const __attribute__((address_space(1))) void*)(x1 + (size_t)(m0 + row) * 256 + lch * 8),
            (__attribute__((address_space(3))) void*)(&Xs[s * 8]), 16, 0, 0);
    }
    // stage Ws: 4096 slots
#pragma unroll
    for (int p = 0; p < 16; ++p) {
        const int s = p * 256 + tid;
        const int row = s >> 5;
        const int c = s & 31;
        const int lch = (c & 24) | ((c & 7) ^ (row & 7));
        __builtin_amdgcn_global_load_lds(
            (const __attribute__((address_space(1))) void*)(w2b + (size_t)row * 256 + lch * 8),
            (__attribute__((address_space(3))) void*)(&Ws[s * 8]), 16, 0, 0);
    }
    __syncthreads();

    // GEMM2: 8 K-frags, 4 MFMA each per wave
    f32x4 acc[4] = {};
#pragma unroll
    for (int h = 0; h < 8; ++h) {
        const int c = h * 4 + quad;
        const int rowa = wM + l16;
        const int pca = (c & 24) | ((c & 7) ^ (rowa & 7));
        bf16x8 a = *(const bf16x8*)&Xs[rowa * 256 + pca * 8];
#pragma unroll
        for (int ni = 0; ni < 4; ++ni) {
            const int rowb = wN + ni * 16 + l16;
            const int pcb = (c & 24) | ((c & 7) ^ (rowb & 7));
            bf16x8 b = *(const bf16x8*)&Ws[rowb * 256 + pcb * 8];
            acc[ni] = __builtin_amdgcn_mfma_f32_16x16x32_bf16(a, b, acc[ni], 0, 0, 0);
        }
    }

    // x2 = gelu(acc + b2) -> X2 (fp32 LDS)
#pragma unroll
    for (int ni = 0; ni < 4; ++ni) {
        const int n = wN + ni * 16 + l16;
        const float bn = b2[n];
#pragma unroll
        for (int rr = 0; rr < 4; ++rr) {
            const int m = wM + quad * 4 + rr;
            X2[m * 128 + n] = gelu_exact(acc[ni][rr] + bn);
        }
    }
    __syncthreads();

    // head: 8 threads per pair, 16 cols each
    const int p = tid >> 3;           // pair-in-block 0..31
    const int cc = (tid & 7) * 16;
    float a0 = 0.f, a1 = 0.f;
#pragma unroll
    for (int j = 0; j < 16; ++j) {
        const float xv = X2[p * 128 + cc + j];
        a0 += xv * W3[cc + j];
        a1 += xv * W3[128 + cc + j];
    }
    a0 += __shfl_xor(a0, 1); a0 += __shfl_xor(a0, 2); a0 += __shfl_xor(a0, 4);
    a1 += __shfl_xor(a1, 1); a1 += __shfl_xor(a1, 2); a1 += __shfl_xor(a1, 4);
    if ((tid & 7) == 0) {
        const int pair = m0 + p;
        const float mk = (mask[pair] >= 0.5f) ? 1.0f : 0.0f;
        out[pair * 2 + 0] = ((1.0f / (1.0f + expf(-(a0 + b3[0])))) * 8.0f + 1.0f) * mk;
        out[pair * 2 + 1] = ((1.0f / (1.0f + expf(-(a1 + b3[1])))) * 8.0f + 1.0f) * mk;
    }
}

// ---------------------------------------------------------------------------
extern "C" void kernel_launch(void* const* d_in, const int* in_sizes, int n_in,
                              void* d_out, int out_size, void* d_ws, size_t ws_size,
                              hipStream_t stream) {
    const float* hs   = (const float*)d_in[0];
    const int*   spans= (const int*)d_in[1];
    const float* mask = (const float*)d_in[2];
    const float* W1   = (const float*)d_in[3];
    const float* b1   = (const float*)d_in[4];
    const float* W2   = (const float*)d_in[5];
    const float* b2   = (const float*)d_in[6];
    const float* W3   = (const float*)d_in[7];
    const float* b3   = (const float*)d_in[8];
    float* out = (float*)d_out;

    // ws: hp bf16 4096x3072 [0, 25165824); w1b bf16 256x3072 [25165824, +1.5MB);
    // x1 bf16 4096x256 [26738688, +2MB); w2b bf16 128x256 [28835840, +64KB).
    unsigned short* hp  = (unsigned short*)d_ws;
    unsigned short* w1b = (unsigned short*)((char*)d_ws + 25165824);
    unsigned short* x1  = (unsigned short*)((char*)d_ws + 26738688);
    unsigned short* w2b = (unsigned short*)((char*)d_ws + 28835840);

    prep_kernel<<<dim3(4896), dim3(256), 0, stream>>>(hs, spans, W1, W2, hp, w1b, w2b);
    gemm1_gelu<<<dim3(128, 4), dim3(256), 0, stream>>>(hp, w1b, b1, x1);
    mlp2_head<<<dim3(128), dim3(256), 0, stream>>>(x1, w2b, b2, W3, b3, mask, out);
}